// Round 2
// baseline (183.083 us; speedup 1.0000x reference)
//
#include <hip/hip_runtime.h>
#include <hip/hip_bf16.h>
#include <math.h>

#define HID 128
#define NPOS 80
#define RPB 4      // batch rows per block (1 per wave)

__device__ __forceinline__ float elu(float x) {
    return x > 0.f ? x : (expf(x) - 1.f);
}

__global__ __launch_bounds__(256) void tle_kernel(
    const int* __restrict__ msg,
    const float* __restrict__ W1, const float* __restrict__ b1,
    const float* __restrict__ W2, const float* __restrict__ b2,
    const float* __restrict__ W3, const float* __restrict__ b3,
    const float* __restrict__ W4, const float* __restrict__ b4,
    float* __restrict__ out)
{
    const int tid  = threadIdx.x;
    const int lane = tid & 63;
    const int w    = tid >> 6;        // wave index = row within block
    const int jj   = lane << 1;       // hidden component pair [jj, jj+1]
    const int b0   = blockIdx.x * RPB;

    __shared__ int   smsg[RPB * NPOS];   // 1.25 KB
    __shared__ float sh[RPB][HID];       // 2 KB

    // Stage this block's message chars (coalesced).
    for (int k = tid; k < RPB * NPOS; k += 256)
        smsg[k] = msg[b0 * NPOS + k];
    __syncthreads();

    // ---- Layer 1: gather-sum of W1 rows, float2 per lane, 8 loads in flight ----
    float hx = b1[jj], hy = b1[jj + 1];
    const int* mrow = &smsg[w * NPOS];

    #pragma unroll 1
    for (int p0 = 0; p0 < NPOS; p0 += 8) {
        int c[8];
        #pragma unroll
        for (int u = 0; u < 8; ++u) c[u] = mrow[p0 + u];     // LDS broadcast
        float2 v[8];
        #pragma unroll
        for (int u = 0; u < 8; ++u)
            v[u] = *(const float2*)&W1[((((p0 + u) << 8) + c[u]) << 7) + jj];
        #pragma unroll
        for (int u = 0; u < 8; ++u) { hx += v[u].x; hy += v[u].y; }
    }
    sh[w][jj]     = elu(hx);
    sh[w][jj + 1] = elu(hy);
    __syncthreads();

    // ---- Dense layers 2..4: matvec, weights coalesced float2, sh broadcast ----
    const float* Ws[3] = { W2, W3, W4 };
    const float* bs[3] = { b2, b3, b4 };
    #pragma unroll 1
    for (int L = 0; L < 3; ++L) {
        const float* __restrict__ W = Ws[L];
        float ax = bs[L][jj], ay = bs[L][jj + 1];

        #pragma unroll 1
        for (int i0 = 0; i0 < HID; i0 += 8) {
            float4 xa = *(const float4*)&sh[w][i0];          // broadcast reads
            float4 xb = *(const float4*)&sh[w][i0 + 4];
            float2 wv[8];
            #pragma unroll
            for (int u = 0; u < 8; ++u)
                wv[u] = *(const float2*)&W[(i0 + u) * HID + jj];
            ax += xa.x * wv[0].x; ay += xa.x * wv[0].y;
            ax += xa.y * wv[1].x; ay += xa.y * wv[1].y;
            ax += xa.z * wv[2].x; ay += xa.z * wv[2].y;
            ax += xa.w * wv[3].x; ay += xa.w * wv[3].y;
            ax += xb.x * wv[4].x; ay += xb.x * wv[4].y;
            ax += xb.y * wv[5].x; ay += xb.y * wv[5].y;
            ax += xb.z * wv[6].x; ay += xb.z * wv[6].y;
            ax += xb.w * wv[7].x; ay += xb.w * wv[7].y;
        }
        __syncthreads();   // all reads of sh done before overwrite
        sh[w][jj]     = elu(ax);
        sh[w][jj + 1] = elu(ay);
        __syncthreads();
    }

    // ---- Store (coalesced float2) ----
    float2 o; o.x = sh[w][jj]; o.y = sh[w][jj + 1];
    *(float2*)&out[(b0 + w) * HID + jj] = o;
}

extern "C" void kernel_launch(void* const* d_in, const int* in_sizes, int n_in,
                              void* d_out, int out_size, void* d_ws, size_t ws_size,
                              hipStream_t stream) {
    const int*   msg = (const int*)  d_in[0];
    const float* W1  = (const float*)d_in[1];
    const float* b1  = (const float*)d_in[2];
    const float* W2  = (const float*)d_in[3];
    const float* b2  = (const float*)d_in[4];
    const float* W3  = (const float*)d_in[5];
    const float* b3  = (const float*)d_in[6];
    const float* W4  = (const float*)d_in[7];
    const float* b4  = (const float*)d_in[8];
    float* out = (float*)d_out;

    const int B = in_sizes[0] / NPOS;          // 8192
    dim3 grid(B / RPB), block(256);
    tle_kernel<<<grid, block, 0, stream>>>(msg, W1, b1, W2, b2, W3, b3, W4, b4, out);
}

// Round 3
// 142.392 us; speedup vs baseline: 1.2858x; 1.2858x over previous
//
#include <hip/hip_runtime.h>
#include <hip/hip_bf16.h>
#include <math.h>

#define HID 128
#define NPOS 80
#define RPB 8      // batch rows per block; 2 rows per wave, 4 waves/block

__device__ __forceinline__ float elu(float x) {
    return x > 0.f ? x : (expf(x) - 1.f);
}

__global__ __launch_bounds__(256) void tle_kernel(
    const int* __restrict__ msg,
    const float* __restrict__ W1, const float* __restrict__ b1,
    const float* __restrict__ W2, const float* __restrict__ b2,
    const float* __restrict__ W3, const float* __restrict__ b3,
    const float* __restrict__ W4, const float* __restrict__ b4,
    float* __restrict__ out)
{
    const int tid  = threadIdx.x;
    const int lane = tid & 63;
    const int w    = tid >> 6;         // wave id: owns rows 2w, 2w+1
    const int jj   = lane << 1;        // hidden pair [jj, jj+1]
    const int b0   = blockIdx.x * RPB;
    const int r0   = 2 * w;
    const int r1   = 2 * w + 1;

    __shared__ int   smsg[RPB * NPOS];   // 2.5 KB
    __shared__ float sh[RPB][HID];       // 4 KB

    // Stage message chars (coalesced). Single barrier in the whole kernel.
    for (int k = tid; k < RPB * NPOS; k += 256)
        smsg[k] = msg[b0 * NPOS + k];
    __syncthreads();

    const int* m0 = &smsg[r0 * NPOS];
    const int* m1 = &smsg[r1 * NPOS];

    // ---- Layer 1: gather-sum of W1 rows; 16 float2 loads in flight ----
    const float b1x = b1[jj], b1y = b1[jj + 1];
    float h0x = b1x, h0y = b1y, h1x = b1x, h1y = b1y;

    #pragma unroll 1
    for (int p0 = 0; p0 < NPOS; p0 += 8) {
        int c0[8], c1[8];
        #pragma unroll
        for (int u = 0; u < 8; ++u) { c0[u] = m0[p0 + u]; c1[u] = m1[p0 + u]; }
        float2 v0[8], v1[8];
        #pragma unroll
        for (int u = 0; u < 8; ++u) {
            const int p = p0 + u;
            v0[u] = *(const float2*)&W1[(p << 15) + (c0[u] << 7) + jj];
            v1[u] = *(const float2*)&W1[(p << 15) + (c1[u] << 7) + jj];
        }
        #pragma unroll
        for (int u = 0; u < 8; ++u) {
            h0x += v0[u].x; h0y += v0[u].y;
            h1x += v1[u].x; h1y += v1[u].y;
        }
    }
    // This wave exclusively owns rows r0, r1 of sh — no cross-wave sync needed.
    *(float2*)&sh[r0][jj] = make_float2(elu(h0x), elu(h0y));
    *(float2*)&sh[r1][jj] = make_float2(elu(h1x), elu(h1y));

    // ---- Dense layers 2..4: wave-local matvec, no barriers ----
    const float* Ws[3] = { W2, W3, W4 };
    const float* bs[3] = { b2, b3, b4 };
    #pragma unroll 1
    for (int L = 0; L < 3; ++L) {
        const float* __restrict__ W = Ws[L];
        const float bx = bs[L][jj], by = bs[L][jj + 1];
        float a0x = bx, a0y = by, a1x = bx, a1y = by;

        #pragma unroll 1
        for (int i0 = 0; i0 < HID; i0 += 8) {
            float4 xa0 = *(const float4*)&sh[r0][i0];       // wave-uniform: LDS broadcast
            float4 xb0 = *(const float4*)&sh[r0][i0 + 4];
            float4 xa1 = *(const float4*)&sh[r1][i0];
            float4 xb1 = *(const float4*)&sh[r1][i0 + 4];
            float2 wv[8];
            #pragma unroll
            for (int u = 0; u < 8; ++u)
                wv[u] = *(const float2*)&W[(i0 + u) * HID + jj];
            a0x += xa0.x * wv[0].x; a0y += xa0.x * wv[0].y;
            a1x += xa1.x * wv[0].x; a1y += xa1.x * wv[0].y;
            a0x += xa0.y * wv[1].x; a0y += xa0.y * wv[1].y;
            a1x += xa1.y * wv[1].x; a1y += xa1.y * wv[1].y;
            a0x += xa0.z * wv[2].x; a0y += xa0.z * wv[2].y;
            a1x += xa1.z * wv[2].x; a1y += xa1.z * wv[2].y;
            a0x += xa0.w * wv[3].x; a0y += xa0.w * wv[3].y;
            a1x += xa1.w * wv[3].x; a1y += xa1.w * wv[3].y;
            a0x += xb0.x * wv[4].x; a0y += xb0.x * wv[4].y;
            a1x += xb1.x * wv[4].x; a1y += xb1.x * wv[4].y;
            a0x += xb0.y * wv[5].x; a0y += xb0.y * wv[5].y;
            a1x += xb1.y * wv[5].x; a1y += xb1.y * wv[5].y;
            a0x += xb0.z * wv[6].x; a0y += xb0.z * wv[6].y;
            a1x += xb1.z * wv[6].x; a1y += xb1.z * wv[6].y;
            a0x += xb0.w * wv[7].x; a0y += xb0.w * wv[7].y;
            a1x += xb1.w * wv[7].x; a1y += xb1.w * wv[7].y;
        }
        // Lockstep within the wave: all reads above retire before these writes.
        *(float2*)&sh[r0][jj] = make_float2(elu(a0x), elu(a0y));
        *(float2*)&sh[r1][jj] = make_float2(elu(a1x), elu(a1y));
    }

    // ---- Store (coalesced float2) ----
    *(float2*)&out[(b0 + r0) * HID + jj] = *(const float2*)&sh[r0][jj];
    *(float2*)&out[(b0 + r1) * HID + jj] = *(const float2*)&sh[r1][jj];
}

extern "C" void kernel_launch(void* const* d_in, const int* in_sizes, int n_in,
                              void* d_out, int out_size, void* d_ws, size_t ws_size,
                              hipStream_t stream) {
    const int*   msg = (const int*)  d_in[0];
    const float* W1  = (const float*)d_in[1];
    const float* b1  = (const float*)d_in[2];
    const float* W2  = (const float*)d_in[3];
    const float* b2  = (const float*)d_in[4];
    const float* W3  = (const float*)d_in[5];
    const float* b3  = (const float*)d_in[6];
    const float* W4  = (const float*)d_in[7];
    const float* b4  = (const float*)d_in[8];
    float* out = (float*)d_out;

    const int B = in_sizes[0] / NPOS;          // 8192
    dim3 grid(B / RPB), block(256);
    tle_kernel<<<grid, block, 0, stream>>>(msg, W1, b1, W2, b2, W3, b3, W4, b4, out);
}